// Round 12
// baseline (261.368 us; speedup 1.0000x reference)
//
#include <hip/hip_runtime.h>
#include <hip/hip_fp16.h>

#define B_ 64
#define L_ 512
#define T_ 128
#define NTHR 128    // 2 waves; one tag j per thread; no global loads in scan loop

typedef _Float16 h2v __attribute__((ext_vector_type(2)));
typedef __fp16   h2b __attribute__((ext_vector_type(2)));
typedef unsigned int u32x4 __attribute__((ext_vector_type(4)));

#define SMEM_EMIT   0                       // [L_][T_] __half, pre-exp'd: 131072 B
#define SMEM_MASK   (L_ * T_ * 2)           // [L_] int: 2048 B
#define SMEM_XBUF   (SMEM_MASK + L_ * 4)    // [2][T_] __half: 512 B
#define SMEM_SHALF  (SMEM_XBUF + 512)       // [2][2] float
#define SMEM_REDX   (SMEM_SHALF + 16)       // [4] float
#define SMEM_BYTES  (SMEM_REDX + 16)

__device__ __forceinline__ float dot2_acc(unsigned int e, unsigned int a, float c) {
#if __has_builtin(__builtin_amdgcn_fdot2)
    h2v ev = __builtin_bit_cast(h2v, e);
    h2v av = __builtin_bit_cast(h2v, a);
    return __builtin_amdgcn_fdot2(ev, av, c, false);
#else
    __half2 eh = __builtin_bit_cast(__half2, e);
    __half2 ah = __builtin_bit_cast(__half2, a);
    float2 ef = __half22float2(eh), af = __half22float2(ah);
    return c + ef.x * af.x + ef.y * af.y;
#endif
}

__device__ __forceinline__ unsigned int pack2(float a, float b) {
#if __has_builtin(__builtin_amdgcn_cvt_pkrtz)
    h2b h = __builtin_amdgcn_cvt_pkrtz(a, b);
    return __builtin_bit_cast(unsigned int, h);
#else
    __half2 h = __floats2half2_rn(a, b);
    return __builtin_bit_cast(unsigned int, h);
#endif
}

// ---- pure-VALU wave-64 sum via DPP; total lands in lane 63 ----
template <int CTRL, int RMASK>
__device__ __forceinline__ float dpp_add(float v) {
    int t = __builtin_amdgcn_update_dpp(0, __builtin_bit_cast(int, v),
                                        CTRL, RMASK, 0xf, true);
    return v + __builtin_bit_cast(float, t);
}
__device__ __forceinline__ float wave_sum_lane63(float v) {
    v = dpp_add<0x111, 0xf>(v);   // row_shr:1
    v = dpp_add<0x112, 0xf>(v);   // row_shr:2
    v = dpp_add<0x114, 0xf>(v);   // row_shr:4
    v = dpp_add<0x118, 0xf>(v);   // row_shr:8  -> lanes 15/31/47/63 = row sums
    v = dpp_add<0x142, 0xa>(v);   // row_bcast:15 -> rows 1,3
    v = dpp_add<0x143, 0xc>(v);   // row_bcast:31 -> lane 63 = wave total
    return v;
}

__global__ __launch_bounds__(NTHR, 1) void crf_nll_kernel(
        const float* __restrict__ feats,   // [B, L, T]
        const float* __restrict__ trans,   // [T, T]
        const int*   __restrict__ tags,    // [B, L]
        const int*   __restrict__ mask,    // [B, L]
        float*       __restrict__ out)     // [B]
{
    extern __shared__ __align__(16) unsigned char smem[];
    __half*       emitS = (__half*)(smem + SMEM_EMIT);   // exp(feats[b]) as f16
    int*          maskS = (int*)(smem + SMEM_MASK);
    __half*       xh    = (__half*)(smem + SMEM_XBUF);   // x vector, double-buffered
    float*        Shalf = (float*)(smem + SMEM_SHALF);   // per-wave half sums
    float*        redx  = (float*)(smem + SMEM_REDX);

    const int tid  = threadIdx.x;
    const int lane = tid & 63;
    const int w    = tid >> 6;
    const int j    = tid;                 // this thread's tag column
    const int b    = blockIdx.x;

    const float* featb = feats + (size_t)b * L_ * T_;
    const int*   maskb = mask + b * L_;
    const int*   tagb  = tags + b * L_;

    // ---- E column j in registers: 16 named u32x4 = 64 VGPR (f16x2 over i-pairs) ----
    u32x4 ec_0, ec_1, ec_2, ec_3, ec_4, ec_5, ec_6, ec_7,
          ec_8, ec_9, ec_10, ec_11, ec_12, ec_13, ec_14, ec_15;
#define INIT_Q(k) { \
        float r0 = trans[(8 * (k) + 0) * T_ + j]; \
        float r1 = trans[(8 * (k) + 1) * T_ + j]; \
        float r2 = trans[(8 * (k) + 2) * T_ + j]; \
        float r3 = trans[(8 * (k) + 3) * T_ + j]; \
        float r4 = trans[(8 * (k) + 4) * T_ + j]; \
        float r5 = trans[(8 * (k) + 5) * T_ + j]; \
        float r6 = trans[(8 * (k) + 6) * T_ + j]; \
        float r7 = trans[(8 * (k) + 7) * T_ + j]; \
        ec_##k.x = pack2(__expf(r0), __expf(r1)); \
        ec_##k.y = pack2(__expf(r2), __expf(r3)); \
        ec_##k.z = pack2(__expf(r4), __expf(r5)); \
        ec_##k.w = pack2(__expf(r6), __expf(r7)); }
    INIT_Q(0)  INIT_Q(1)  INIT_Q(2)  INIT_Q(3)
    INIT_Q(4)  INIT_Q(5)  INIT_Q(6)  INIT_Q(7)
    INIT_Q(8)  INIT_Q(9)  INIT_Q(10) INIT_Q(11)
    INIT_Q(12) INIT_Q(13) INIT_Q(14) INIT_Q(15)
#undef INIT_Q

    // ---- stage exp(feats[b]) -> emitS (f16), mask -> maskS ----
    {
        const float4* f4 = (const float4*)featb;
        uint2* e2 = (uint2*)emitS;
        for (int i = tid; i < (L_ * T_) / 4; i += NTHR) {
            float4 v = f4[i];
            unsigned int lo = pack2(__expf(v.x), __expf(v.y));
            unsigned int hi = pack2(__expf(v.z), __expf(v.w));
            e2[i] = make_uint2(lo, hi);
        }
        for (int i = tid; i < L_; i += NTHR) maskS[i] = maskb[i];
    }

    // ---- init: alpha_0 = emit_0 ----
    float e0 = featb[j];
    {
        float v = e0;
        #pragma unroll
        for (int off = 32; off >= 1; off >>= 1) v = fmaxf(v, __shfl_xor(v, off));
        if (lane == 0) redx[w] = v;
    }
    __syncthreads();                       // publish staging + redx
    const float m0 = fmaxf(redx[0], redx[1]);
    float xc = __expf(e0 - m0);
    float N  = m0;                         // running log-normalizer (uniform)
    xh[j] = __float2half(xc);              // xbuf slot 0
    {
        float s = wave_sum_lane63(xc);
        if (lane == 63) { Shalf[0 + w] = s; Shalf[2 + w] = s; }
    }
    __syncthreads();                       // publish xbuf0 + Shalf

    const float LOG128 = 4.8520302639196171f;
    int pr = 0;
    const __half* erow = emitS + T_;       // row t = 1

#define DOTQ(k) { \
        u32x4 a4 = ap[(k)];                       \
        a0 = dot2_acc(ec_##k.x, a4.x, a0);        \
        a1 = dot2_acc(ec_##k.y, a4.y, a1);        \
        a2 = dot2_acc(ec_##k.z, a4.z, a2);        \
        a3 = dot2_acc(ec_##k.w, a4.w, a3); }

    // ---- forward scan: pure LDS + VALU, one raw barrier per step ----
    for (int t = 1; t < L_; ++t) {
        // stale S (written pre-barrier at step t-1; slot t&1)
        const float2 sh = *(const float2*)&Shalf[(t & 1) * 2];
        const float exq = __half2float(erow[j]);
        const int   mcur = maskS[t];

        float a0 = 0.f, a1 = 0.f, a2 = 0.f, a3 = 0.f;
        const u32x4* ap = (const u32x4*)(xh + pr * T_);
        DOTQ(0)  DOTQ(1)  DOTQ(2)  DOTQ(3)
        DOTQ(4)  DOTQ(5)  DOTQ(6)  DOTQ(7)
        DOTQ(8)  DOTQ(9)  DOTQ(10) DOTQ(11)
        DOTQ(12) DOTQ(13) DOTQ(14) DOTQ(15)
        const float ssum = (a0 + a1) + (a2 + a3);

        const float Stot = sh.x + sh.y;
        const float rcpC = 1.0f / (Stot * 128.0f);
        const float logC = __logf(Stot) + LOG128;
        const float x = ssum * exq * rcpC;
        if (mcur) { xc = x; N += logC; }

        xh[(pr ^ 1) * T_ + j] = __float2half(xc);
        float sl = wave_sum_lane63(xc);             // exact sum, consumed at t+1
        if (lane == 63) Shalf[((t + 1) & 1) * 2 + w] = sl;

        asm volatile("s_waitcnt lgkmcnt(0)" ::: "memory");
        __builtin_amdgcn_s_barrier();
        __builtin_amdgcn_sched_barrier(0);
        pr ^= 1;
        erow += T_;
    }
#undef DOTQ

    // ---- norm = N + log(sum of final x) ----
    {
        float fs = wave_sum_lane63(xc);
        if (lane == 63) redx[w] = fs;
    }
    __syncthreads();
    const float norm = N + __logf(redx[0] + redx[1]);

    // ---- gold path score (128 threads) ----
    float g = 0.f;
    for (int tt = tid; tt < L_; tt += NTHR) {
        int tg = tagb[tt];
        g += featb[tt * T_ + tg] * (float)maskb[tt];
        if (tt + 1 < L_) {
            g += trans[tg * T_ + tagb[tt + 1]] * (float)maskb[tt + 1];
        }
    }
    #pragma unroll
    for (int off = 32; off >= 1; off >>= 1) g += __shfl_xor(g, off);
    if (lane == 0) redx[2 + w] = g;
    __syncthreads();

    if (tid == 0) out[b] = norm - (redx[2] + redx[3]);
}

extern "C" void kernel_launch(void* const* d_in, const int* in_sizes, int n_in,
                              void* d_out, int out_size, void* d_ws, size_t ws_size,
                              hipStream_t stream) {
    const float* feats = (const float*)d_in[0];
    const float* trans = (const float*)d_in[1];
    const int*   tags  = (const int*)d_in[2];
    const int*   mask  = (const int*)d_in[3];
    float* out = (float*)d_out;

    hipFuncSetAttribute((const void*)crf_nll_kernel,
                        hipFuncAttributeMaxDynamicSharedMemorySize, SMEM_BYTES);
    crf_nll_kernel<<<B_, NTHR, SMEM_BYTES, stream>>>(feats, trans, tags, mask, out);
}